// Round 16
// baseline (702.932 us; speedup 1.0000x reference)
//
#include <hip/hip_runtime.h>
#include <math.h>

#define Bb 8
#define Nn 1024
#define Kk 32
#define Dd 256
#define Hh 8
#define DHh 32
#define TDIMt 16
#define NBnb 32
#define HIDh 128
#define NSns 128
#define SHDs 9
#define EINe 304   // NB + TDIM + 2*NS
#define NCOLS 1536 // vproj 256 | hsrc 128 | hdst 128 | qw 1024

typedef __bf16 bf16_t;
typedef bf16_t bf16x8 __attribute__((ext_vector_type(8)));
typedef float floatx4 __attribute__((ext_vector_type(4)));

__device__ __forceinline__ float gelu_fast(float x){
  float g = 1.5957691216057308f*(x + 0.044715f*x*x*x);
  return x*__builtin_amdgcn_rcpf(1.0f + __expf(-g));
}
__device__ __forceinline__ float tanh_fast(float x){
  return 1.0f - 2.0f*__builtin_amdgcn_rcpf(1.0f + __expf(2.0f*x));
}

// ---------------- setup: knn FIRST, then preps, then embed ----------------
__global__ __launch_bounds__(256) void setup_kernel(
    const float* __restrict__ x, const float* __restrict__ y, const float* __restrict__ t,
    const float* __restrict__ We, const float* __restrict__ Wk1, const float* __restrict__ bk1,
    const float* __restrict__ Wk2, const float* __restrict__ Wq, const float* __restrict__ Wv,
    const float* __restrict__ Wo,
    bf16_t* __restrict__ Wt, bf16_t* __restrict__ Wto, bf16_t* __restrict__ WrbfT,
    float* __restrict__ t_hd, int* __restrict__ src,
    float* __restrict__ node, bf16_t* __restrict__ node_bf){

  __shared__ float s_b[32];
  const int bid = blockIdx.x, tid = threadIdx.x;

  if (bid < 2048){                       // ---- knn (one wave per node)
    int wave = tid >> 6, lane = tid & 63;
    int bn = bid*4 + wave;
    int b = bn >> 10, n = bn & (Nn-1);
    const float* xb = x + (size_t)b*Nn*3;
    float px = xb[n*3+0], py = xb[n*3+1], pz = xb[n*3+2];
    float d2v[16];
    #pragma unroll
    for (int i=0;i<16;i++){
      int j = i*64 + lane;
      float dx = px - xb[j*3+0];
      float dy = py - xb[j*3+1];
      float dz = pz - xb[j*3+2];
      d2v[i] = dx*dx + dy*dy + dz*dz;
    }
    for (int s=0;s<Kk;s++){
      float best = 3.0e38f; int bslot = 0;
      #pragma unroll
      for (int i=0;i<16;i++){
        if (d2v[i] < best){ best = d2v[i]; bslot = i; }
      }
      int bj = bslot*64 + lane;
      #pragma unroll
      for (int off=32; off>=1; off>>=1){
        float ov = __shfl_xor(best, off);
        int   oj = __shfl_xor(bj,   off);
        if (ov < best || (ov == best && oj < bj)){ best = ov; bj = oj; }
      }
      if ((bj & 63) == lane){
        int sl = bj >> 6;
        #pragma unroll
        for (int i=0;i<16;i++) if (i==sl) d2v[i] = 3.0e38f;
      }
      if (lane == 0) src[(size_t)bn*Kk + s] = bj;
    }
  } else if (bid < 6144){                // ---- wprepM (coalesced)
    int i = bid-2048; int l = i>>10, yy = i&1023;
    int h = yy>>7, c = yy&127;
    if (tid < 32) s_b[tid] = Wk2[(size_t)l*HIDh*Dd + (size_t)c*Dd + h*DHh + tid];
    __syncthreads();
    const int rloc = tid>>3, dg = tid&7;
    const float b0 = s_b[dg*4+0], b1 = s_b[dg*4+1], b2 = s_b[dg*4+2], b3 = s_b[dg*4+3];
    #pragma unroll
    for (int p=0;p<8;p++){
      int ii = p*32 + rloc;
      const float4 v = *(const float4*)(Wq + (size_t)l*Dd*Dd + (size_t)ii*Dd + h*DHh + dg*4);
      float part = v.x*b0 + v.y*b1 + v.z*b2 + v.w*b3;
      part += __shfl_xor(part, 1);
      part += __shfl_xor(part, 2);
      part += __shfl_xor(part, 4);
      if (dg == 0) Wt[((size_t)l*NCOLS + 512 + yy)*Dd + ii] = (bf16_t)part;
    }
  } else if (bid < 8192){                // ---- wprep: Wt[l][c][k], c<512
    int i = bid-6144; int l = i>>9, c = i&511, k = tid;
    const float* wk1l = Wk1 + (size_t)l*EINe*HIDh;
    float v;
    if (c < 256)       v = Wv[(size_t)l*265*Dd + (size_t)k*Dd + c];
    else if (c < 384){ int c2 = c-256; v = (k < 128) ? wk1l[(48+k)*HIDh + c2] : 0.0f; }
    else             { int c2 = c-384; v = (k < 128) ? wk1l[(176+k)*HIDh + c2] : 0.0f; }
    Wt[((size_t)l*NCOLS + c)*Dd + k] = (bf16_t)v;
  } else if (bid < 8960){                // ---- wprepO
    int i = bid-8192; int l = i>>8; int c = i&255; int k = tid;
    Wto[((size_t)l*Dd + c)*Dd + k] = (bf16_t)Wo[(size_t)l*Dd*Dd + (size_t)k*Dd + c];
  } else if (bid < 9024){                // ---- wprepR
    int i = bid-8960; int l = i>>4, cg = i&15;
    int c = cg*8 + (tid>>5), k = tid&31;
    WrbfT[((size_t)l*HIDh + c)*NBnb + k] = (bf16_t)Wk1[(size_t)l*EINe*HIDh + (size_t)k*HIDh + c];
  } else if (bid < 9040){                // ---- tprep
    int i = bid-9024; int pair = i*2 + (tid>>7);
    int l = pair>>3, b = pair&7, c = tid&127;
    const float* wk1l = Wk1 + (size_t)l*EINe*HIDh;
    float a = bk1[l*HIDh + c];
    #pragma unroll
    for (int ii=0;ii<TDIMt;ii++) a += t[b*TDIMt+ii]*wk1l[(32+ii)*HIDh + c];
    t_hd[(l*Bb + b)*HIDh + c] = a;
  } else {                               // ---- embed (4 nodes/block)
    int bn0 = (bid-9040)*4; int c = tid;
    float w0 = We[0*Dd+c], w1 = We[1*Dd+c], w2 = We[2*Dd+c];
    float wt[TDIMt];
    #pragma unroll
    for (int i=0;i<TDIMt;i++) wt[i] = We[(3+i)*Dd+c];
    #pragma unroll
    for (int u=0;u<4;u++){
      int bn = bn0 + u; int b = bn >> 10;
      float a = y[(size_t)bn*3+0]*w0 + y[(size_t)bn*3+1]*w1 + y[(size_t)bn*3+2]*w2;
      #pragma unroll
      for (int i=0;i<TDIMt;i++) a += t[b*TDIMt+i]*wt[i];
      node[(size_t)bn*Dd + c] = a;
      node_bf[(size_t)bn*Dd + c] = (bf16_t)a;
    }
  }
}

// ---------------- proj GEMM (layer 0 only); hdst gets +t_hd folded in ----------------
__global__ __launch_bounds__(256) void gemm_proj(const bf16_t* __restrict__ A,
    const bf16_t* __restrict__ Wt_all, float* __restrict__ vproj_f,
    bf16_t* __restrict__ hsrc_bf, float* __restrict__ hdst_f,
    bf16_t* __restrict__ qw_bf, const float* __restrict__ t_hd, int layer){
  const int tid = threadIdx.x;
  const int wave = tid>>6, lane = tid&63;
  const int row16 = lane&15, quad = lane>>4;
  const int m_base = blockIdx.x*128 + wave*32;
  const int n_base = blockIdx.y*64;
  const bf16_t* Bw = Wt_all + (size_t)layer*NCOLS*Dd;

  floatx4 acc[2][4];
  #pragma unroll
  for (int mi=0;mi<2;mi++)
    #pragma unroll
    for (int ni=0;ni<4;ni++){ floatx4 z = {0.f,0.f,0.f,0.f}; acc[mi][ni] = z; }

  const bf16_t* a0p = A  + (size_t)(m_base + row16)*Dd + quad*8;
  const bf16_t* bp  = Bw + (size_t)(n_base + row16)*Dd + quad*8;
  #pragma unroll
  for (int ks=0; ks<8; ks++){
    bf16x8 a0 = *(const bf16x8*)(a0p + ks*32);
    bf16x8 a1 = *(const bf16x8*)(a0p + 16*Dd + ks*32);
    #pragma unroll
    for (int ni=0;ni<4;ni++){
      bf16x8 b = *(const bf16x8*)(bp + (size_t)ni*16*Dd + ks*32);
      acc[0][ni] = __builtin_amdgcn_mfma_f32_16x16x32_bf16(a0, b, acc[0][ni], 0,0,0);
      acc[1][ni] = __builtin_amdgcn_mfma_f32_16x16x32_bf16(a1, b, acc[1][ni], 0,0,0);
    }
  }

  const int by = blockIdx.y;
  const int bb = m_base >> 10;
  #pragma unroll
  for (int mi=0;mi<2;mi++)
    #pragma unroll
    for (int ni=0;ni<4;ni++){
      int col = n_base + ni*16 + row16;
      #pragma unroll
      for (int r=0;r<4;r++){
        int row = m_base + mi*16 + quad*4 + r;
        float v = acc[mi][ni][r];
        if (by < 4)       vproj_f[(size_t)row*256 + col]        = v;
        else if (by < 6)  hsrc_bf[(size_t)row*128 + (col-256)]  = (bf16_t)v;
        else if (by < 8)  hdst_f[(size_t)row*128 + (col-384)]   = v + t_hd[(size_t)(layer*Bb + bb)*HIDh + (col-384)];
        else              qw_bf[(size_t)row*1024 + (col-512)]   = (bf16_t)v;
      }
    }
}

// ---------------- fused upd(lu) + proj(lp=lu+1): 32 node rows per block ----------------
__global__ __launch_bounds__(256) void gemm_updproj(
    const bf16_t* __restrict__ agg_bf, const bf16_t* __restrict__ Wto,
    float* __restrict__ node, const bf16_t* __restrict__ Wt_all,
    float* __restrict__ vproj_f, bf16_t* __restrict__ hsrc_bf,
    float* __restrict__ hdst_f, bf16_t* __restrict__ qw_bf,
    const float* __restrict__ t_hd, int lu){

  __shared__ __align__(16) bf16_t s_n[32*264];
  const int tid = threadIdx.x;
  const int wave = tid>>6, lane = tid&63;
  const int row16 = lane&15, quad = lane>>4;
  const int m0 = blockIdx.x*32;
  const int lp = lu + 1;
  const int bb = m0 >> 10;

  // ---- Phase U ----
  {
    const bf16_t* Bw = Wto + (size_t)lu*Dd*Dd;
    floatx4 acc[2][4];
    #pragma unroll
    for (int mi=0;mi<2;mi++)
      #pragma unroll
      for (int ni=0;ni<4;ni++){ floatx4 z = {0.f,0.f,0.f,0.f}; acc[mi][ni] = z; }
    const bf16_t* a0p = agg_bf + (size_t)(m0 + row16)*Dd + quad*8;
    const bf16_t* bp  = Bw + (size_t)(wave*64 + row16)*Dd + quad*8;
    #pragma unroll
    for (int ks=0; ks<8; ks++){
      bf16x8 a0 = *(const bf16x8*)(a0p + ks*32);
      bf16x8 a1 = *(const bf16x8*)(a0p + 16*Dd + ks*32);
      #pragma unroll
      for (int ni=0;ni<4;ni++){
        bf16x8 b = *(const bf16x8*)(bp + (size_t)ni*16*Dd + ks*32);
        acc[0][ni] = __builtin_amdgcn_mfma_f32_16x16x32_bf16(a0, b, acc[0][ni], 0,0,0);
        acc[1][ni] = __builtin_amdgcn_mfma_f32_16x16x32_bf16(a1, b, acc[1][ni], 0,0,0);
      }
    }
    #pragma unroll
    for (int mi=0;mi<2;mi++)
      #pragma unroll
      for (int ni=0;ni<4;ni++){
        int col = wave*64 + ni*16 + row16;
        #pragma unroll
        for (int r=0;r<4;r++){
          int lr  = mi*16 + quad*4 + r;
          int row = m0 + lr;
          float v = acc[mi][ni][r] + node[(size_t)row*Dd + col];
          if (col < 64)       v = gelu_fast(v);
          else if (col < 128) v = tanh_fast(v);
          node[(size_t)row*Dd + col] = v;
          s_n[lr*264 + col] = (bf16_t)v;
        }
      }
  }
  __syncthreads();

  // ---- Phase P ----
  #pragma unroll 1
  for (int c=0; c<6; c++){
    const int colbase = c*256 + wave*64;
    floatx4 acc[2][4];
    #pragma unroll
    for (int mi=0;mi<2;mi++)
      #pragma unroll
      for (int ni=0;ni<4;ni++){ floatx4 z = {0.f,0.f,0.f,0.f}; acc[mi][ni] = z; }
    const bf16_t* bp = Wt_all + (size_t)lp*NCOLS*Dd + (size_t)(colbase + row16)*Dd + quad*8;
    #pragma unroll
    for (int ks=0; ks<8; ks++){
      bf16x8 a0 = *(const bf16x8*)&s_n[row16*264 + quad*8 + ks*32];
      bf16x8 a1 = *(const bf16x8*)&s_n[(16+row16)*264 + quad*8 + ks*32];
      #pragma unroll
      for (int ni=0;ni<4;ni++){
        bf16x8 b = *(const bf16x8*)(bp + (size_t)ni*16*Dd + ks*32);
        acc[0][ni] = __builtin_amdgcn_mfma_f32_16x16x32_bf16(a0, b, acc[0][ni], 0,0,0);
        acc[1][ni] = __builtin_amdgcn_mfma_f32_16x16x32_bf16(a1, b, acc[1][ni], 0,0,0);
      }
    }
    #pragma unroll
    for (int mi=0;mi<2;mi++)
      #pragma unroll
      for (int ni=0;ni<4;ni++){
        int col = colbase + ni*16 + row16;
        #pragma unroll
        for (int r=0;r<4;r++){
          int row = m0 + mi*16 + quad*4 + r;
          float v = acc[mi][ni][r];
          if (colbase < 256)      vproj_f[(size_t)row*256 + col]       = v;
          else if (colbase < 384) hsrc_bf[(size_t)row*128 + (col-256)] = (bf16_t)v;
          else if (colbase < 512) hdst_f[(size_t)row*128 + (col-384)]  = v + t_hd[(size_t)(lp*Bb + bb)*HIDh + (col-384)];
          else                    qw_bf[(size_t)row*1024 + (col-512)]  = (bf16_t)v;
        }
      }
  }
}

// ---------------- attn: TWO nodes per block, SEQUENTIAL (same LDS/VGPR as 1-node) ----------------
__global__ __launch_bounds__(256) void attn_kernel(
    const float* __restrict__ x, const int* __restrict__ src,
    const float* __restrict__ vproj_f, const bf16_t* __restrict__ hsrc_bf,
    const float* __restrict__ hdst_f, const bf16_t* __restrict__ qw_bf,
    const bf16_t* __restrict__ WrbfT,
    const float* __restrict__ Wvg, const float* __restrict__ Woo,
    bf16_t* __restrict__ agg_bf, float* __restrict__ out, int layer){

  __shared__ __align__(16) char smem[11632];
  bf16_t* s_h     = (bf16_t*)(smem);
  float*  s_sh    = (float*)(smem + 8704);
  float*  s_cut   = (float*)(smem + 9984);
  int*    s_srcv  = (int*)  (smem + 10112);
  float*  s_logit = (float*)(smem + 10240);
  float*  s_poolsh= (float*)(smem + 11264);
  float*  s_red   = (float*)(smem + 11584);

  const int tid = threadIdx.x;
  const int wave = tid>>6, lane = tid&63;
  const int row16 = lane&15, quad = lane>>4;

  #pragma unroll 1
  for (int u=0; u<2; u++){
    const int bn = blockIdx.x*2 + u;
    const int b  = bn >> 10;

    const float ax = x[(size_t)bn*3+0], ay = x[(size_t)bn*3+1], az = x[(size_t)bn*3+2];

    const int hr = tid>>4;
    const int hc = tid&15;
    const int sH0 = src[(size_t)bn*Kk + hr];
    const int sH1 = src[(size_t)bn*Kk + hr + 16];
    const int sE0 = src[(size_t)bn*Kk + row16];
    const int sE1 = src[(size_t)bn*Kk + row16 + 16];
    bf16x8 hsv0 = *(const bf16x8*)(hsrc_bf + ((size_t)b*Nn + sH0)*128 + hc*8);
    bf16x8 hsv1 = *(const bf16x8*)(hsrc_bf + ((size_t)b*Nn + sH1)*128 + hc*8);

    // rbf A-fragments via Gaussian recurrence
    bf16x8 a0f, a1f;
    {
      const float* xj0 = x + ((size_t)b*Nn + sE0)*3;
      const float* xj1 = x + ((size_t)b*Nn + sE1)*3;
      float d0x = ax - xj0[0], d0y = ay - xj0[1], d0z = az - xj0[2];
      float d1x = ax - xj1[0], d1y = ay - xj1[1], d1z = az - xj1[2];
      float rr0 = sqrtf(d0x*d0x + d0y*d0y + d0z*d0z);
      float rr1 = sqrtf(d1x*d1x + d1y*d1y + d1z*d1z);
      float xx0 = 10.0f*(1.0f - rr0*0.5f);
      float xx1 = 10.0f*(1.0f - rr1*0.5f);
      float cu0 = (xx0 > 0.0f) ? 1.4f*__expf(-__builtin_amdgcn_rcpf(xx0)) : 0.0f;
      float cu1 = (xx1 > 0.0f) ? 1.4f*__expf(-__builtin_amdgcn_rcpf(xx1)) : 0.0f;
      float sc0 = 4.798224586623f*cu0;
      float sc1 = 4.798224586623f*cu1;
      float rs0 = fminf(rr0*15.5f, 33.0f);
      float rs1 = fminf(rr1*15.5f, 33.0f);
      float cbase = (float)(quad*8);
      float dd0 = rs0 - cbase, dd1 = rs1 - cbase;
      float e0 = __expf(-dd0*dd0)*sc0;
      float e1 = __expf(-dd1*dd1)*sc1;
      float g0 = __expf(2.0f*dd0 - 1.0f);
      float g1 = __expf(2.0f*dd1 - 1.0f);
      a0f[0] = (bf16_t)e0; a1f[0] = (bf16_t)e1;
      #pragma unroll
      for (int j=1;j<8;j++){
        e0 *= g0; e1 *= g1;
        a0f[j] = (bf16_t)e0; a1f[j] = (bf16_t)e1;
        g0 *= 0.13533528323661270f; g1 *= 0.13533528323661270f;
      }
    }

    if (tid < 32){
      int k = tid;
      int j = src[(size_t)bn*Kk + k];
      s_srcv[k] = j;
      const float* xj = x + ((size_t)b*Nn + j)*3;
      float dx = ax - xj[0], dy = ay - xj[1], dz = az - xj[2];
      float rr = sqrtf(dx*dx + dy*dy + dz*dz);
      float xx = 10.0f*(1.0f - rr*0.5f);
      s_cut[k] = (xx > 0.0f) ? 1.4f*__expf(-__builtin_amdgcn_rcpf(xx)) : 0.0f;
    } else if (tid < 64){
      int k = tid - 32;
      int j = src[(size_t)bn*Kk + k];
      const float* xj = x + ((size_t)b*Nn + j)*3;
      float dx = ax - xj[0], dy = ay - xj[1], dz = az - xj[2];
      float rr = sqrtf(dx*dx + dy*dy + dz*dz);
      float inv = __builtin_amdgcn_rcpf(fmaxf(rr, 1e-9f));
      float ux = dx*inv, uy = dy*inv, uz = dz*inv;
      float* sh = s_sh + k*10;
      sh[0] = 1.0f;
      sh[1] = 1.7320508075688772f*ux;
      sh[2] = 1.7320508075688772f*uy;
      sh[3] = 1.7320508075688772f*uz;
      sh[4] = 3.872983346207417f*ux*uy;
      sh[5] = 3.872983346207417f*uy*uz;
      sh[6] = 1.118033988749895f*(3.0f*uz*uz - 1.0f);
      sh[7] = 3.872983346207417f*ux*uz;
      sh[8] = 1.9364916731037085f*(ux*ux - uy*uy);
    }

    floatx4 acc[2][2];
    {
      #pragma unroll
      for (int mi=0;mi<2;mi++)
        #pragma unroll
        for (int ni=0;ni<2;ni++){ floatx4 z = {0.f,0.f,0.f,0.f}; acc[mi][ni] = z; }
      const bf16_t* bp = WrbfT + ((size_t)layer*HIDh + wave*32 + row16)*NBnb + quad*8;
      bf16x8 b0 = *(const bf16x8*)(bp);
      bf16x8 b1 = *(const bf16x8*)(bp + 16*NBnb);
      acc[0][0] = __builtin_amdgcn_mfma_f32_16x16x32_bf16(a0f, b0, acc[0][0], 0,0,0);
      acc[0][1] = __builtin_amdgcn_mfma_f32_16x16x32_bf16(a0f, b1, acc[0][1], 0,0,0);
      acc[1][0] = __builtin_amdgcn_mfma_f32_16x16x32_bf16(a1f, b0, acc[1][0], 0,0,0);
      acc[1][1] = __builtin_amdgcn_mfma_f32_16x16x32_bf16(a1f, b1, acc[1][1], 0,0,0);
    }
    *(bf16x8*)(s_h + hr*136 + hc*8)      = hsv0;
    *(bf16x8*)(s_h + (hr+16)*136 + hc*8) = hsv1;
    __syncthreads();

    // epilogue: h = gelu(acc + hd + hs), in place (hdst_f already includes t_hd)
    #pragma unroll
    for (int ni=0;ni<2;ni++){
      int c = wave*32 + ni*16 + row16;
      float hdv = hdst_f[(size_t)bn*128 + c];
      #pragma unroll
      for (int mi=0;mi<2;mi++){
        #pragma unroll
        for (int r=0;r<4;r++){
          int e = mi*16 + quad*4 + r;
          float hs = (float)s_h[e*136 + c];
          s_h[e*136 + c] = (bf16_t)gelu_fast(acc[mi][ni][r] + hdv + hs);
        }
      }
    }
    __syncthreads();

    if (wave < 2){
      floatx4 la = {0.f,0.f,0.f,0.f};
      const bf16_t* qp = qw_bf + (size_t)bn*1024 + row16*HIDh + quad*8;
      #pragma unroll
      for (int ks=0; ks<4; ks++){
        bf16x8 a = *(const bf16x8*)(s_h + (wave*16 + row16)*136 + ks*32 + quad*8);
        bf16x8 bq = *(const bf16x8*)(qp + ks*32);
        la = __builtin_amdgcn_mfma_f32_16x16x32_bf16(a, bq, la, 0,0,0);
      }
      if (row16 < Hh){
        #pragma unroll
        for (int r=0;r<4;r++)
          s_logit[(wave*16 + quad*4 + r)*8 + row16] = la[r]*0.17677669529663687f;
      }
    }
    __syncthreads();

    {
      const int l = tid & 63;
      const int k = l & 31;
      const int h = tid >> 5;
      float lv = s_logit[k*8 + h];
      float m = lv;
      #pragma unroll
      for (int off=16; off>=1; off>>=1) m = fmaxf(m, __shfl_xor(m, off));
      float w = s_cut[k]*__expf(lv - m);
      float ss = w;
      #pragma unroll
      for (int off=16; off>=1; off>>=1) ss += __shfl_xor(ss, off);
      float alpha = w*__builtin_amdgcn_rcpf(ss + 1e-9f);

      s_logit[k*8 + h] = alpha;   // same half-wave group re-reads below: in-order within wave

      const int sgi = (k < SHDs) ? k : 0;
      float a_m0 = 0.0f, a_m1 = 0.0f, a_sh = 0.0f;
      #pragma unroll
      for (int kk=0; kk<Kk; kk+=2){
        float av0 = s_logit[kk*8 + h];
        float av1 = s_logit[(kk+1)*8 + h];
        a_m0 += av0 * vproj_f[((size_t)b*Nn + s_srcv[kk])*256 + tid];
        a_m1 += av1 * vproj_f[((size_t)b*Nn + s_srcv[kk+1])*256 + tid];
        a_sh += av0 * s_sh[kk*10 + sgi] + av1 * s_sh[(kk+1)*10 + sgi];
      }
      float a_main = a_m0 + a_m1;
      if (k < SHDs) s_poolsh[h*10 + k] = a_sh;

      const float* wvsh = Wvg + (size_t)layer*265*Dd + 256*Dd;
      #pragma unroll
      for (int sg=0; sg<SHDs; sg++) a_main += s_poolsh[h*10 + sg]*wvsh[sg*Dd + tid];

      if (layer < 3){
        agg_bf[(size_t)bn*Dd + tid] = (bf16_t)a_main;
      } else {
        float p0 = a_main*Woo[tid*3+0];
        float p1 = a_main*Woo[tid*3+1];
        float p2 = a_main*Woo[tid*3+2];
        #pragma unroll
        for (int off=32; off>=1; off>>=1){
          p0 += __shfl_xor(p0, off);
          p1 += __shfl_xor(p1, off);
          p2 += __shfl_xor(p2, off);
        }
        if (lane == 0){ s_red[wave*3+0]=p0; s_red[wave*3+1]=p1; s_red[wave*3+2]=p2; }
        __syncthreads();
        if (tid < 3)
          out[(size_t)bn*3 + tid] = s_red[0*3+tid]+s_red[1*3+tid]+s_red[2*3+tid]+s_red[3*3+tid];
      }
    }
    __syncthreads();  // LDS reuse fence before next node
  }
}

extern "C" void kernel_launch(void* const* d_in, const int* in_sizes, int n_in,
                              void* d_out, int out_size, void* d_ws, size_t ws_size,
                              hipStream_t stream){
  const float* x   = (const float*)d_in[0];
  const float* y   = (const float*)d_in[1];
  const float* t   = (const float*)d_in[2];
  const float* We  = (const float*)d_in[3];
  const float* Wk1 = (const float*)d_in[4];
  const float* bk1 = (const float*)d_in[5];
  const float* Wk2 = (const float*)d_in[6];
  const float* Wq  = (const float*)d_in[7];
  const float* Wv  = (const float*)d_in[8];
  const float* Wo  = (const float*)d_in[9];
  const float* Woo = (const float*)d_in[10];
  float* out = (float*)d_out;

  char* ws = (char*)d_ws;
  size_t off = 0;
  auto take = [&](size_t bytes)->char*{ char* p = ws + off; off = (off + bytes + 255) & ~(size_t)255; return p; };

  int*    src      = (int*)   take((size_t)Bb*Nn*Kk*4);
  float*  node     = (float*) take((size_t)Bb*Nn*Dd*4);
  bf16_t* node_bf  = (bf16_t*)take((size_t)Bb*Nn*Dd*2);
  bf16_t* agg_bf   = (bf16_t*)take((size_t)Bb*Nn*Dd*2);
  float*  vproj_f  = (float*) take((size_t)Bb*Nn*256*4);
  bf16_t* hsrc_bf  = (bf16_t*)take((size_t)Bb*Nn*128*2);
  float*  hdst_f   = (float*) take((size_t)Bb*Nn*128*4);
  bf16_t* qw_bf    = (bf16_t*)take(((size_t)Bb*Nn*1024 + 2048)*2);  // +pad for B-frag overread
  bf16_t* Wt       = (bf16_t*)take((size_t)4*NCOLS*Dd*2);
  bf16_t* Wto      = (bf16_t*)take((size_t)3*Dd*Dd*2);
  bf16_t* WrbfT    = (bf16_t*)take((size_t)4*HIDh*NBnb*2);
  float*  t_hd     = (float*) take((size_t)4*Bb*HIDh*4);

  setup_kernel<<<dim3(11088), 256, 0, stream>>>(x, y, t, We, Wk1, bk1, Wk2, Wq, Wv, Wo,
                                                Wt, Wto, WrbfT, t_hd, src, node, node_bf);

  gemm_proj<<<dim3(64,24), 256, 0, stream>>>(node_bf, Wt, vproj_f, hsrc_bf, hdst_f, qw_bf, t_hd, 0);
  attn_kernel<<<dim3(Bb*Nn/2), 256, 0, stream>>>(x, src, vproj_f, hsrc_bf, hdst_f, qw_bf,
                                                 WrbfT, Wv, Woo, agg_bf, out, 0);
  for (int l=1; l<4; l++){
    gemm_updproj<<<dim3(Bb*Nn/32), 256, 0, stream>>>(agg_bf, Wto, node, Wt,
                                                     vproj_f, hsrc_bf, hdst_f, qw_bf, t_hd, l-1);
    attn_kernel<<<dim3(Bb*Nn/2), 256, 0, stream>>>(x, src, vproj_f, hsrc_bf, hdst_f, qw_bf,
                                                   WrbfT, Wv, Woo, agg_bf, out, l);
  }
}

// Round 17
// 581.784 us; speedup vs baseline: 1.2082x; 1.2082x over previous
//
#include <hip/hip_runtime.h>
#include <math.h>

#define Bb 8
#define Nn 1024
#define Kk 32
#define Dd 256
#define Hh 8
#define DHh 32
#define TDIMt 16
#define NBnb 32
#define HIDh 128
#define NSns 128
#define SHDs 9
#define EINe 304   // NB + TDIM + 2*NS
#define NCOLS 1536 // vproj 256 | hsrc 128 | hdst 128 | qw 1024

typedef __bf16 bf16_t;
typedef bf16_t bf16x8 __attribute__((ext_vector_type(8)));
typedef float floatx4 __attribute__((ext_vector_type(4)));

__device__ __forceinline__ float gelu_fast(float x){
  float g = 1.5957691216057308f*(x + 0.044715f*x*x*x);
  return x*__builtin_amdgcn_rcpf(1.0f + __expf(-g));
}
__device__ __forceinline__ float tanh_fast(float x){
  return 1.0f - 2.0f*__builtin_amdgcn_rcpf(1.0f + __expf(2.0f*x));
}

// ---------------- setup: knn FIRST, then preps, then embed ----------------
__global__ __launch_bounds__(256) void setup_kernel(
    const float* __restrict__ x, const float* __restrict__ y, const float* __restrict__ t,
    const float* __restrict__ We, const float* __restrict__ Wk1, const float* __restrict__ bk1,
    const float* __restrict__ Wk2, const float* __restrict__ Wq, const float* __restrict__ Wv,
    const float* __restrict__ Wo,
    bf16_t* __restrict__ Wt, bf16_t* __restrict__ Wto, bf16_t* __restrict__ WrbfT,
    float* __restrict__ t_hd, int* __restrict__ src,
    float* __restrict__ node, bf16_t* __restrict__ node_bf){

  __shared__ float s_b[32];
  const int bid = blockIdx.x, tid = threadIdx.x;

  if (bid < 2048){                       // ---- knn (one wave per node)
    int wave = tid >> 6, lane = tid & 63;
    int bn = bid*4 + wave;
    int b = bn >> 10, n = bn & (Nn-1);
    const float* xb = x + (size_t)b*Nn*3;
    float px = xb[n*3+0], py = xb[n*3+1], pz = xb[n*3+2];
    float d2v[16];
    #pragma unroll
    for (int i=0;i<16;i++){
      int j = i*64 + lane;
      float dx = px - xb[j*3+0];
      float dy = py - xb[j*3+1];
      float dz = pz - xb[j*3+2];
      d2v[i] = dx*dx + dy*dy + dz*dz;
    }
    for (int s=0;s<Kk;s++){
      float best = 3.0e38f; int bslot = 0;
      #pragma unroll
      for (int i=0;i<16;i++){
        if (d2v[i] < best){ best = d2v[i]; bslot = i; }
      }
      int bj = bslot*64 + lane;
      #pragma unroll
      for (int off=32; off>=1; off>>=1){
        float ov = __shfl_xor(best, off);
        int   oj = __shfl_xor(bj,   off);
        if (ov < best || (ov == best && oj < bj)){ best = ov; bj = oj; }
      }
      if ((bj & 63) == lane){
        int sl = bj >> 6;
        #pragma unroll
        for (int i=0;i<16;i++) if (i==sl) d2v[i] = 3.0e38f;
      }
      if (lane == 0) src[(size_t)bn*Kk + s] = bj;
    }
  } else if (bid < 6144){                // ---- wprepM (coalesced)
    int i = bid-2048; int l = i>>10, yy = i&1023;
    int h = yy>>7, c = yy&127;
    if (tid < 32) s_b[tid] = Wk2[(size_t)l*HIDh*Dd + (size_t)c*Dd + h*DHh + tid];
    __syncthreads();
    const int rloc = tid>>3, dg = tid&7;
    const float b0 = s_b[dg*4+0], b1 = s_b[dg*4+1], b2 = s_b[dg*4+2], b3 = s_b[dg*4+3];
    #pragma unroll
    for (int p=0;p<8;p++){
      int ii = p*32 + rloc;
      const float4 v = *(const float4*)(Wq + (size_t)l*Dd*Dd + (size_t)ii*Dd + h*DHh + dg*4);
      float part = v.x*b0 + v.y*b1 + v.z*b2 + v.w*b3;
      part += __shfl_xor(part, 1);
      part += __shfl_xor(part, 2);
      part += __shfl_xor(part, 4);
      if (dg == 0) Wt[((size_t)l*NCOLS + 512 + yy)*Dd + ii] = (bf16_t)part;
    }
  } else if (bid < 8192){                // ---- wprep: Wt[l][c][k], c<512
    int i = bid-6144; int l = i>>9, c = i&511, k = tid;
    const float* wk1l = Wk1 + (size_t)l*EINe*HIDh;
    float v;
    if (c < 256)       v = Wv[(size_t)l*265*Dd + (size_t)k*Dd + c];
    else if (c < 384){ int c2 = c-256; v = (k < 128) ? wk1l[(48+k)*HIDh + c2] : 0.0f; }
    else             { int c2 = c-384; v = (k < 128) ? wk1l[(176+k)*HIDh + c2] : 0.0f; }
    Wt[((size_t)l*NCOLS + c)*Dd + k] = (bf16_t)v;
  } else if (bid < 8960){                // ---- wprepO
    int i = bid-8192; int l = i>>8; int c = i&255; int k = tid;
    Wto[((size_t)l*Dd + c)*Dd + k] = (bf16_t)Wo[(size_t)l*Dd*Dd + (size_t)k*Dd + c];
  } else if (bid < 9024){                // ---- wprepR
    int i = bid-8960; int l = i>>4, cg = i&15;
    int c = cg*8 + (tid>>5), k = tid&31;
    WrbfT[((size_t)l*HIDh + c)*NBnb + k] = (bf16_t)Wk1[(size_t)l*EINe*HIDh + (size_t)k*HIDh + c];
  } else if (bid < 9040){                // ---- tprep
    int i = bid-9024; int pair = i*2 + (tid>>7);
    int l = pair>>3, b = pair&7, c = tid&127;
    const float* wk1l = Wk1 + (size_t)l*EINe*HIDh;
    float a = bk1[l*HIDh + c];
    #pragma unroll
    for (int ii=0;ii<TDIMt;ii++) a += t[b*TDIMt+ii]*wk1l[(32+ii)*HIDh + c];
    t_hd[(l*Bb + b)*HIDh + c] = a;
  } else {                               // ---- embed (4 nodes/block)
    int bn0 = (bid-9040)*4; int c = tid;
    float w0 = We[0*Dd+c], w1 = We[1*Dd+c], w2 = We[2*Dd+c];
    float wt[TDIMt];
    #pragma unroll
    for (int i=0;i<TDIMt;i++) wt[i] = We[(3+i)*Dd+c];
    #pragma unroll
    for (int u=0;u<4;u++){
      int bn = bn0 + u; int b = bn >> 10;
      float a = y[(size_t)bn*3+0]*w0 + y[(size_t)bn*3+1]*w1 + y[(size_t)bn*3+2]*w2;
      #pragma unroll
      for (int i=0;i<TDIMt;i++) a += t[b*TDIMt+i]*wt[i];
      node[(size_t)bn*Dd + c] = a;
      node_bf[(size_t)bn*Dd + c] = (bf16_t)a;
    }
  }
}

// ---------------- proj GEMM (layer 0 only); hdst gets +t_hd folded in ----------------
__global__ __launch_bounds__(256) void gemm_proj(const bf16_t* __restrict__ A,
    const bf16_t* __restrict__ Wt_all, float* __restrict__ vproj_f,
    bf16_t* __restrict__ hsrc_bf, float* __restrict__ hdst_f,
    bf16_t* __restrict__ qw_bf, const float* __restrict__ t_hd, int layer){
  const int tid = threadIdx.x;
  const int wave = tid>>6, lane = tid&63;
  const int row16 = lane&15, quad = lane>>4;
  const int m_base = blockIdx.x*128 + wave*32;
  const int n_base = blockIdx.y*64;
  const bf16_t* Bw = Wt_all + (size_t)layer*NCOLS*Dd;

  floatx4 acc[2][4];
  #pragma unroll
  for (int mi=0;mi<2;mi++)
    #pragma unroll
    for (int ni=0;ni<4;ni++){ floatx4 z = {0.f,0.f,0.f,0.f}; acc[mi][ni] = z; }

  const bf16_t* a0p = A  + (size_t)(m_base + row16)*Dd + quad*8;
  const bf16_t* bp  = Bw + (size_t)(n_base + row16)*Dd + quad*8;
  #pragma unroll
  for (int ks=0; ks<8; ks++){
    bf16x8 a0 = *(const bf16x8*)(a0p + ks*32);
    bf16x8 a1 = *(const bf16x8*)(a0p + 16*Dd + ks*32);
    #pragma unroll
    for (int ni=0;ni<4;ni++){
      bf16x8 b = *(const bf16x8*)(bp + (size_t)ni*16*Dd + ks*32);
      acc[0][ni] = __builtin_amdgcn_mfma_f32_16x16x32_bf16(a0, b, acc[0][ni], 0,0,0);
      acc[1][ni] = __builtin_amdgcn_mfma_f32_16x16x32_bf16(a1, b, acc[1][ni], 0,0,0);
    }
  }

  const int by = blockIdx.y;
  const int bb = m_base >> 10;
  #pragma unroll
  for (int mi=0;mi<2;mi++)
    #pragma unroll
    for (int ni=0;ni<4;ni++){
      int col = n_base + ni*16 + row16;
      #pragma unroll
      for (int r=0;r<4;r++){
        int row = m_base + mi*16 + quad*4 + r;
        float v = acc[mi][ni][r];
        if (by < 4)       vproj_f[(size_t)row*256 + col]        = v;
        else if (by < 6)  hsrc_bf[(size_t)row*128 + (col-256)]  = (bf16_t)v;
        else if (by < 8)  hdst_f[(size_t)row*128 + (col-384)]   = v + t_hd[(size_t)(layer*Bb + bb)*HIDh + (col-384)];
        else              qw_bf[(size_t)row*1024 + (col-512)]   = (bf16_t)v;
      }
    }
}

// ---------------- fused upd(lu) + proj(lp=lu+1): 32 node rows per block ----------------
__global__ __launch_bounds__(256) void gemm_updproj(
    const bf16_t* __restrict__ agg_bf, const bf16_t* __restrict__ Wto,
    float* __restrict__ node, const bf16_t* __restrict__ Wt_all,
    float* __restrict__ vproj_f, bf16_t* __restrict__ hsrc_bf,
    float* __restrict__ hdst_f, bf16_t* __restrict__ qw_bf,
    const float* __restrict__ t_hd, int lu, int write_node){

  __shared__ __align__(16) bf16_t s_n[32*264];
  const int tid = threadIdx.x;
  const int wave = tid>>6, lane = tid&63;
  const int row16 = lane&15, quad = lane>>4;
  const int m0 = blockIdx.x*32;
  const int lp = lu + 1;
  const int bb = m0 >> 10;

  // ---- Phase U ----
  {
    const bf16_t* Bw = Wto + (size_t)lu*Dd*Dd;
    floatx4 acc[2][4];
    #pragma unroll
    for (int mi=0;mi<2;mi++)
      #pragma unroll
      for (int ni=0;ni<4;ni++){ floatx4 z = {0.f,0.f,0.f,0.f}; acc[mi][ni] = z; }
    const bf16_t* a0p = agg_bf + (size_t)(m0 + row16)*Dd + quad*8;
    const bf16_t* bp  = Bw + (size_t)(wave*64 + row16)*Dd + quad*8;
    #pragma unroll
    for (int ks=0; ks<8; ks++){
      bf16x8 a0 = *(const bf16x8*)(a0p + ks*32);
      bf16x8 a1 = *(const bf16x8*)(a0p + 16*Dd + ks*32);
      #pragma unroll
      for (int ni=0;ni<4;ni++){
        bf16x8 b = *(const bf16x8*)(bp + (size_t)ni*16*Dd + ks*32);
        acc[0][ni] = __builtin_amdgcn_mfma_f32_16x16x32_bf16(a0, b, acc[0][ni], 0,0,0);
        acc[1][ni] = __builtin_amdgcn_mfma_f32_16x16x32_bf16(a1, b, acc[1][ni], 0,0,0);
      }
    }
    #pragma unroll
    for (int mi=0;mi<2;mi++)
      #pragma unroll
      for (int ni=0;ni<4;ni++){
        int col = wave*64 + ni*16 + row16;
        #pragma unroll
        for (int r=0;r<4;r++){
          int lr  = mi*16 + quad*4 + r;
          int row = m0 + lr;
          float v = acc[mi][ni][r] + node[(size_t)row*Dd + col];
          if (col < 64)       v = gelu_fast(v);
          else if (col < 128) v = tanh_fast(v);
          if (write_node) node[(size_t)row*Dd + col] = v;
          s_n[lr*264 + col] = (bf16_t)v;
        }
      }
  }
  __syncthreads();

  // ---- Phase P ----
  #pragma unroll 1
  for (int c=0; c<6; c++){
    const int colbase = c*256 + wave*64;
    floatx4 acc[2][4];
    #pragma unroll
    for (int mi=0;mi<2;mi++)
      #pragma unroll
      for (int ni=0;ni<4;ni++){ floatx4 z = {0.f,0.f,0.f,0.f}; acc[mi][ni] = z; }
    const bf16_t* bp = Wt_all + (size_t)lp*NCOLS*Dd + (size_t)(colbase + row16)*Dd + quad*8;
    #pragma unroll
    for (int ks=0; ks<8; ks++){
      bf16x8 a0 = *(const bf16x8*)&s_n[row16*264 + quad*8 + ks*32];
      bf16x8 a1 = *(const bf16x8*)&s_n[(16+row16)*264 + quad*8 + ks*32];
      #pragma unroll
      for (int ni=0;ni<4;ni++){
        bf16x8 b = *(const bf16x8*)(bp + (size_t)ni*16*Dd + ks*32);
        acc[0][ni] = __builtin_amdgcn_mfma_f32_16x16x32_bf16(a0, b, acc[0][ni], 0,0,0);
        acc[1][ni] = __builtin_amdgcn_mfma_f32_16x16x32_bf16(a1, b, acc[1][ni], 0,0,0);
      }
    }
    #pragma unroll
    for (int mi=0;mi<2;mi++)
      #pragma unroll
      for (int ni=0;ni<4;ni++){
        int col = colbase + ni*16 + row16;
        #pragma unroll
        for (int r=0;r<4;r++){
          int row = m0 + mi*16 + quad*4 + r;
          float v = acc[mi][ni][r];
          if (colbase < 256)      vproj_f[(size_t)row*256 + col]       = v;
          else if (colbase < 384) hsrc_bf[(size_t)row*128 + (col-256)] = (bf16_t)v;
          else if (colbase < 512) hdst_f[(size_t)row*128 + (col-384)]  = v + t_hd[(size_t)(lp*Bb + bb)*HIDh + (col-384)];
          else                    qw_bf[(size_t)row*1024 + (col-512)]  = (bf16_t)v;
        }
      }
  }
}

// ---------------- attn: block per node ----------------
__global__ __launch_bounds__(256) void attn_kernel(
    const float* __restrict__ x, const int* __restrict__ src,
    const float* __restrict__ vproj_f, const bf16_t* __restrict__ hsrc_bf,
    const float* __restrict__ hdst_f, const bf16_t* __restrict__ qw_bf,
    const bf16_t* __restrict__ WrbfT,
    const float* __restrict__ Wvg, const float* __restrict__ Woo,
    bf16_t* __restrict__ agg_bf, float* __restrict__ out, int layer){

  __shared__ __align__(16) char smem[11632];
  bf16_t* s_h     = (bf16_t*)(smem);
  float*  s_sh    = (float*)(smem + 8704);
  float*  s_cut   = (float*)(smem + 9984);
  int*    s_srcv  = (int*)  (smem + 10112);
  float*  s_logit = (float*)(smem + 10240);
  float*  s_poolsh= (float*)(smem + 11264);
  float*  s_red   = (float*)(smem + 11584);

  const int tid = threadIdx.x;
  const int bn  = blockIdx.x;
  const int b   = bn >> 10;
  const int wave = tid>>6, lane = tid&63;
  const int row16 = lane&15, quad = lane>>4;

  const float ax = x[(size_t)bn*3+0], ay = x[(size_t)bn*3+1], az = x[(size_t)bn*3+2];

  const int hr = tid>>4;
  const int hc = tid&15;
  const int sH0 = src[(size_t)bn*Kk + hr];
  const int sH1 = src[(size_t)bn*Kk + hr + 16];
  const int sE0 = src[(size_t)bn*Kk + row16];
  const int sE1 = src[(size_t)bn*Kk + row16 + 16];
  bf16x8 hsv0 = *(const bf16x8*)(hsrc_bf + ((size_t)b*Nn + sH0)*128 + hc*8);
  bf16x8 hsv1 = *(const bf16x8*)(hsrc_bf + ((size_t)b*Nn + sH1)*128 + hc*8);

  // rbf A-fragments via Gaussian recurrence
  bf16x8 a0f, a1f;
  {
    const float* xj0 = x + ((size_t)b*Nn + sE0)*3;
    const float* xj1 = x + ((size_t)b*Nn + sE1)*3;
    float d0x = ax - xj0[0], d0y = ay - xj0[1], d0z = az - xj0[2];
    float d1x = ax - xj1[0], d1y = ay - xj1[1], d1z = az - xj1[2];
    float rr0 = sqrtf(d0x*d0x + d0y*d0y + d0z*d0z);
    float rr1 = sqrtf(d1x*d1x + d1y*d1y + d1z*d1z);
    float xx0 = 10.0f*(1.0f - rr0*0.5f);
    float xx1 = 10.0f*(1.0f - rr1*0.5f);
    float cu0 = (xx0 > 0.0f) ? 1.4f*__expf(-__builtin_amdgcn_rcpf(xx0)) : 0.0f;
    float cu1 = (xx1 > 0.0f) ? 1.4f*__expf(-__builtin_amdgcn_rcpf(xx1)) : 0.0f;
    float sc0 = 4.798224586623f*cu0;
    float sc1 = 4.798224586623f*cu1;
    float rs0 = fminf(rr0*15.5f, 33.0f);
    float rs1 = fminf(rr1*15.5f, 33.0f);
    float cbase = (float)(quad*8);
    float dd0 = rs0 - cbase, dd1 = rs1 - cbase;
    float e0 = __expf(-dd0*dd0)*sc0;
    float e1 = __expf(-dd1*dd1)*sc1;
    float g0 = __expf(2.0f*dd0 - 1.0f);
    float g1 = __expf(2.0f*dd1 - 1.0f);
    a0f[0] = (bf16_t)e0; a1f[0] = (bf16_t)e1;
    #pragma unroll
    for (int j=1;j<8;j++){
      e0 *= g0; e1 *= g1;
      a0f[j] = (bf16_t)e0; a1f[j] = (bf16_t)e1;
      g0 *= 0.13533528323661270f; g1 *= 0.13533528323661270f;
    }
  }

  if (tid < 32){
    int k = tid;
    int j = src[(size_t)bn*Kk + k];
    s_srcv[k] = j;
    const float* xj = x + ((size_t)b*Nn + j)*3;
    float dx = ax - xj[0], dy = ay - xj[1], dz = az - xj[2];
    float rr = sqrtf(dx*dx + dy*dy + dz*dz);
    float xx = 10.0f*(1.0f - rr*0.5f);
    s_cut[k] = (xx > 0.0f) ? 1.4f*__expf(-__builtin_amdgcn_rcpf(xx)) : 0.0f;
  } else if (tid < 64){
    int k = tid - 32;
    int j = src[(size_t)bn*Kk + k];
    const float* xj = x + ((size_t)b*Nn + j)*3;
    float dx = ax - xj[0], dy = ay - xj[1], dz = az - xj[2];
    float rr = sqrtf(dx*dx + dy*dy + dz*dz);
    float inv = __builtin_amdgcn_rcpf(fmaxf(rr, 1e-9f));
    float ux = dx*inv, uy = dy*inv, uz = dz*inv;
    float* sh = s_sh + k*10;
    sh[0] = 1.0f;
    sh[1] = 1.7320508075688772f*ux;
    sh[2] = 1.7320508075688772f*uy;
    sh[3] = 1.7320508075688772f*uz;
    sh[4] = 3.872983346207417f*ux*uy;
    sh[5] = 3.872983346207417f*uy*uz;
    sh[6] = 1.118033988749895f*(3.0f*uz*uz - 1.0f);
    sh[7] = 3.872983346207417f*ux*uz;
    sh[8] = 1.9364916731037085f*(ux*ux - uy*uy);
  }

  floatx4 acc[2][2];
  {
    #pragma unroll
    for (int mi=0;mi<2;mi++)
      #pragma unroll
      for (int ni=0;ni<2;ni++){ floatx4 z = {0.f,0.f,0.f,0.f}; acc[mi][ni] = z; }
    const bf16_t* bp = WrbfT + ((size_t)layer*HIDh + wave*32 + row16)*NBnb + quad*8;
    bf16x8 b0 = *(const bf16x8*)(bp);
    bf16x8 b1 = *(const bf16x8*)(bp + 16*NBnb);
    acc[0][0] = __builtin_amdgcn_mfma_f32_16x16x32_bf16(a0f, b0, acc[0][0], 0,0,0);
    acc[0][1] = __builtin_amdgcn_mfma_f32_16x16x32_bf16(a0f, b1, acc[0][1], 0,0,0);
    acc[1][0] = __builtin_amdgcn_mfma_f32_16x16x32_bf16(a1f, b0, acc[1][0], 0,0,0);
    acc[1][1] = __builtin_amdgcn_mfma_f32_16x16x32_bf16(a1f, b1, acc[1][1], 0,0,0);
  }
  *(bf16x8*)(s_h + hr*136 + hc*8)      = hsv0;
  *(bf16x8*)(s_h + (hr+16)*136 + hc*8) = hsv1;
  __syncthreads();

  #pragma unroll
  for (int ni=0;ni<2;ni++){
    int c = wave*32 + ni*16 + row16;
    float hdv = hdst_f[(size_t)bn*128 + c];
    #pragma unroll
    for (int mi=0;mi<2;mi++){
      #pragma unroll
      for (int r=0;r<4;r++){
        int e = mi*16 + quad*4 + r;
        float hs = (float)s_h[e*136 + c];
        s_h[e*136 + c] = (bf16_t)gelu_fast(acc[mi][ni][r] + hdv + hs);
      }
    }
  }
  __syncthreads();

  if (wave < 2){
    floatx4 la = {0.f,0.f,0.f,0.f};
    const bf16_t* qp = qw_bf + (size_t)bn*1024 + row16*HIDh + quad*8;
    #pragma unroll
    for (int ks=0; ks<4; ks++){
      bf16x8 a = *(const bf16x8*)(s_h + (wave*16 + row16)*136 + ks*32 + quad*8);
      bf16x8 bq = *(const bf16x8*)(qp + ks*32);
      la = __builtin_amdgcn_mfma_f32_16x16x32_bf16(a, bq, la, 0,0,0);
    }
    if (row16 < Hh){
      #pragma unroll
      for (int r=0;r<4;r++)
        s_logit[(wave*16 + quad*4 + r)*8 + row16] = la[r]*0.17677669529663687f;
    }
  }
  __syncthreads();

  {
    const int l = tid & 63;
    const int k = l & 31;
    const int h = tid >> 5;
    float lv = s_logit[k*8 + h];
    float m = lv;
    #pragma unroll
    for (int off=16; off>=1; off>>=1) m = fmaxf(m, __shfl_xor(m, off));
    float w = s_cut[k]*__expf(lv - m);
    float ss = w;
    #pragma unroll
    for (int off=16; off>=1; off>>=1) ss += __shfl_xor(ss, off);
    float alpha = w*__builtin_amdgcn_rcpf(ss + 1e-9f);

    s_logit[k*8 + h] = alpha;   // same half-wave group re-reads below: in-order within wave

    const int sgi = (k < SHDs) ? k : 0;
    float a_m0 = 0.0f, a_m1 = 0.0f, a_sh = 0.0f;
    #pragma unroll
    for (int kk=0; kk<Kk; kk+=2){
      float av0 = s_logit[kk*8 + h];
      float av1 = s_logit[(kk+1)*8 + h];
      a_m0 += av0 * vproj_f[((size_t)b*Nn + s_srcv[kk])*256 + tid];
      a_m1 += av1 * vproj_f[((size_t)b*Nn + s_srcv[kk+1])*256 + tid];
      a_sh += av0 * s_sh[kk*10 + sgi] + av1 * s_sh[(kk+1)*10 + sgi];
    }
    float a_main = a_m0 + a_m1;
    if (k < SHDs) s_poolsh[h*10 + k] = a_sh;

    const float* wvsh = Wvg + (size_t)layer*265*Dd + 256*Dd;
    #pragma unroll
    for (int sg=0; sg<SHDs; sg++) a_main += s_poolsh[h*10 + sg]*wvsh[sg*Dd + tid];

    if (layer < 3){
      agg_bf[(size_t)bn*Dd + tid] = (bf16_t)a_main;
    } else {
      float p0 = a_main*Woo[tid*3+0];
      float p1 = a_main*Woo[tid*3+1];
      float p2 = a_main*Woo[tid*3+2];
      #pragma unroll
      for (int off=32; off>=1; off>>=1){
        p0 += __shfl_xor(p0, off);
        p1 += __shfl_xor(p1, off);
        p2 += __shfl_xor(p2, off);
      }
      if (lane == 0){ s_red[wave*3+0]=p0; s_red[wave*3+1]=p1; s_red[wave*3+2]=p2; }
      __syncthreads();
      if (tid < 3)
        out[(size_t)bn*3 + tid] = s_red[0*3+tid]+s_red[1*3+tid]+s_red[2*3+tid]+s_red[3*3+tid];
    }
  }
}

extern "C" void kernel_launch(void* const* d_in, const int* in_sizes, int n_in,
                              void* d_out, int out_size, void* d_ws, size_t ws_size,
                              hipStream_t stream){
  const float* x   = (const float*)d_in[0];
  const float* y   = (const float*)d_in[1];
  const float* t   = (const float*)d_in[2];
  const float* We  = (const float*)d_in[3];
  const float* Wk1 = (const float*)d_in[4];
  const float* bk1 = (const float*)d_in[5];
  const float* Wk2 = (const float*)d_in[6];
  const float* Wq  = (const float*)d_in[7];
  const float* Wv  = (const float*)d_in[8];
  const float* Wo  = (const float*)d_in[9];
  const float* Woo = (const float*)d_in[10];
  float* out = (float*)d_out;

  char* ws = (char*)d_ws;
  size_t off = 0;
  auto take = [&](size_t bytes)->char*{ char* p = ws + off; off = (off + bytes + 255) & ~(size_t)255; return p; };

  int*    src      = (int*)   take((size_t)Bb*Nn*Kk*4);
  float*  node     = (float*) take((size_t)Bb*Nn*Dd*4);
  bf16_t* node_bf  = (bf16_t*)take((size_t)Bb*Nn*Dd*2);
  bf16_t* agg_bf   = (bf16_t*)take((size_t)Bb*Nn*Dd*2);
  float*  vproj_f  = (float*) take((size_t)Bb*Nn*256*4);
  bf16_t* hsrc_bf  = (bf16_t*)take((size_t)Bb*Nn*128*2);
  float*  hdst_f   = (float*) take((size_t)Bb*Nn*128*4);
  bf16_t* qw_bf    = (bf16_t*)take(((size_t)Bb*Nn*1024 + 2048)*2);  // +pad for B-frag overread
  bf16_t* Wt       = (bf16_t*)take((size_t)4*NCOLS*Dd*2);
  bf16_t* Wto      = (bf16_t*)take((size_t)3*Dd*Dd*2);
  bf16_t* WrbfT    = (bf16_t*)take((size_t)4*HIDh*NBnb*2);
  float*  t_hd     = (float*) take((size_t)4*Bb*HIDh*4);

  setup_kernel<<<dim3(11088), 256, 0, stream>>>(x, y, t, We, Wk1, bk1, Wk2, Wq, Wv, Wo,
                                                Wt, Wto, WrbfT, t_hd, src, node, node_bf);

  gemm_proj<<<dim3(64,24), 256, 0, stream>>>(node_bf, Wt, vproj_f, hsrc_bf, hdst_f, qw_bf, t_hd, 0);
  attn_kernel<<<dim3(Bb*Nn), 256, 0, stream>>>(x, src, vproj_f, hsrc_bf, hdst_f, qw_bf,
                                               WrbfT, Wv, Woo, agg_bf, out, 0);
  for (int l=1; l<4; l++){
    gemm_updproj<<<dim3(Bb*Nn/32), 256, 0, stream>>>(agg_bf, Wto, node, Wt,
                                                     vproj_f, hsrc_bf, hdst_f, qw_bf, t_hd, l-1,
                                                     (l < 3) ? 1 : 0);
    attn_kernel<<<dim3(Bb*Nn), 256, 0, stream>>>(x, src, vproj_f, hsrc_bf, hdst_f, qw_bf,
                                                 WrbfT, Wv, Woo, agg_bf, out, l);
  }
}

// Round 18
// 571.992 us; speedup vs baseline: 1.2289x; 1.0171x over previous
//
#include <hip/hip_runtime.h>
#include <math.h>

#define Bb 8
#define Nn 1024
#define Kk 32
#define Dd 256
#define Hh 8
#define DHh 32
#define TDIMt 16
#define NBnb 32
#define HIDh 128
#define NSns 128
#define SHDs 9
#define EINe 304   // NB + TDIM + 2*NS
#define NCOLS 1536 // vproj 256 | hsrc 128 | hdst 128 | qw 1024

typedef __bf16 bf16_t;
typedef bf16_t bf16x8 __attribute__((ext_vector_type(8)));
typedef float floatx4 __attribute__((ext_vector_type(4)));

__device__ __forceinline__ float gelu_fast(float x){
  float g = 1.5957691216057308f*(x + 0.044715f*x*x*x);
  return x*__builtin_amdgcn_rcpf(1.0f + __expf(-g));
}
__device__ __forceinline__ float tanh_fast(float x){
  return 1.0f - 2.0f*__builtin_amdgcn_rcpf(1.0f + __expf(2.0f*x));
}

// ---------------- setup: knn FIRST, then preps, then embed ----------------
__global__ __launch_bounds__(256) void setup_kernel(
    const float* __restrict__ x, const float* __restrict__ y, const float* __restrict__ t,
    const float* __restrict__ We, const float* __restrict__ Wk1, const float* __restrict__ bk1,
    const float* __restrict__ Wk2, const float* __restrict__ Wq, const float* __restrict__ Wv,
    const float* __restrict__ Wo,
    bf16_t* __restrict__ Wt, bf16_t* __restrict__ Wto, bf16_t* __restrict__ WrbfT,
    float* __restrict__ t_hd, int* __restrict__ src,
    float* __restrict__ node, bf16_t* __restrict__ node_bf){

  __shared__ float s_b[32];
  const int bid = blockIdx.x, tid = threadIdx.x;

  if (bid < 2048){                       // ---- knn (one wave per node, cached local min)
    int wave = tid >> 6, lane = tid & 63;
    int bn = bid*4 + wave;
    int b = bn >> 10, n = bn & (Nn-1);
    const float* xb = x + (size_t)b*Nn*3;
    float px = xb[n*3+0], py = xb[n*3+1], pz = xb[n*3+2];
    float d2v[16];
    #pragma unroll
    for (int i=0;i<16;i++){
      int j = i*64 + lane;
      float dx = px - xb[j*3+0];
      float dy = py - xb[j*3+1];
      float dz = pz - xb[j*3+2];
      d2v[i] = dx*dx + dy*dy + dz*dz;
    }
    float lmin = 3.0e38f; int lslot = 0;
    #pragma unroll
    for (int i=0;i<16;i++){
      if (d2v[i] < lmin){ lmin = d2v[i]; lslot = i; }
    }
    for (int s=0;s<Kk;s++){
      float best = lmin; int bj = lslot*64 + lane;
      #pragma unroll
      for (int off=32; off>=1; off>>=1){
        float ov = __shfl_xor(best, off);
        int   oj = __shfl_xor(bj,   off);
        if (ov < best || (ov == best && oj < bj)){ best = ov; bj = oj; }
      }
      if ((bj & 63) == lane){
        d2v[lslot] = 3.0e38f;
        lmin = 3.0e38f; lslot = 0;
        #pragma unroll
        for (int i=0;i<16;i++){
          if (d2v[i] < lmin){ lmin = d2v[i]; lslot = i; }
        }
      }
      if (lane == 0) src[(size_t)bn*Kk + s] = bj;
    }
  } else if (bid < 6144){                // ---- wprepM (coalesced)
    int i = bid-2048; int l = i>>10, yy = i&1023;
    int h = yy>>7, c = yy&127;
    if (tid < 32) s_b[tid] = Wk2[(size_t)l*HIDh*Dd + (size_t)c*Dd + h*DHh + tid];
    __syncthreads();
    const int rloc = tid>>3, dg = tid&7;
    const float b0 = s_b[dg*4+0], b1 = s_b[dg*4+1], b2 = s_b[dg*4+2], b3 = s_b[dg*4+3];
    #pragma unroll
    for (int p=0;p<8;p++){
      int ii = p*32 + rloc;
      const float4 v = *(const float4*)(Wq + (size_t)l*Dd*Dd + (size_t)ii*Dd + h*DHh + dg*4);
      float part = v.x*b0 + v.y*b1 + v.z*b2 + v.w*b3;
      part += __shfl_xor(part, 1);
      part += __shfl_xor(part, 2);
      part += __shfl_xor(part, 4);
      if (dg == 0) Wt[((size_t)l*NCOLS + 512 + yy)*Dd + ii] = (bf16_t)part;
    }
  } else if (bid < 8192){                // ---- wprep: Wt[l][c][k], c<512
    int i = bid-6144; int l = i>>9, c = i&511, k = tid;
    const float* wk1l = Wk1 + (size_t)l*EINe*HIDh;
    float v;
    if (c < 256)       v = Wv[(size_t)l*265*Dd + (size_t)k*Dd + c];
    else if (c < 384){ int c2 = c-256; v = (k < 128) ? wk1l[(48+k)*HIDh + c2] : 0.0f; }
    else             { int c2 = c-384; v = (k < 128) ? wk1l[(176+k)*HIDh + c2] : 0.0f; }
    Wt[((size_t)l*NCOLS + c)*Dd + k] = (bf16_t)v;
  } else if (bid < 8960){                // ---- wprepO
    int i = bid-8192; int l = i>>8; int c = i&255; int k = tid;
    Wto[((size_t)l*Dd + c)*Dd + k] = (bf16_t)Wo[(size_t)l*Dd*Dd + (size_t)k*Dd + c];
  } else if (bid < 9024){                // ---- wprepR
    int i = bid-8960; int l = i>>4, cg = i&15;
    int c = cg*8 + (tid>>5), k = tid&31;
    WrbfT[((size_t)l*HIDh + c)*NBnb + k] = (bf16_t)Wk1[(size_t)l*EINe*HIDh + (size_t)k*HIDh + c];
  } else if (bid < 9040){                // ---- tprep
    int i = bid-9024; int pair = i*2 + (tid>>7);
    int l = pair>>3, b = pair&7, c = tid&127;
    const float* wk1l = Wk1 + (size_t)l*EINe*HIDh;
    float a = bk1[l*HIDh + c];
    #pragma unroll
    for (int ii=0;ii<TDIMt;ii++) a += t[b*TDIMt+ii]*wk1l[(32+ii)*HIDh + c];
    t_hd[(l*Bb + b)*HIDh + c] = a;
  } else {                               // ---- embed (4 nodes/block)
    int bn0 = (bid-9040)*4; int c = tid;
    float w0 = We[0*Dd+c], w1 = We[1*Dd+c], w2 = We[2*Dd+c];
    float wt[TDIMt];
    #pragma unroll
    for (int i=0;i<TDIMt;i++) wt[i] = We[(3+i)*Dd+c];
    #pragma unroll
    for (int u=0;u<4;u++){
      int bn = bn0 + u; int b = bn >> 10;
      float a = y[(size_t)bn*3+0]*w0 + y[(size_t)bn*3+1]*w1 + y[(size_t)bn*3+2]*w2;
      #pragma unroll
      for (int i=0;i<TDIMt;i++) a += t[b*TDIMt+i]*wt[i];
      node[(size_t)bn*Dd + c] = a;
      node_bf[(size_t)bn*Dd + c] = (bf16_t)a;
    }
  }
}

// ---------------- proj GEMM (layer 0 only); hdst gets +t_hd folded in ----------------
__global__ __launch_bounds__(256) void gemm_proj(const bf16_t* __restrict__ A,
    const bf16_t* __restrict__ Wt_all, float* __restrict__ vproj_f,
    bf16_t* __restrict__ hsrc_bf, float* __restrict__ hdst_f,
    bf16_t* __restrict__ qw_bf, const float* __restrict__ t_hd, int layer){
  const int tid = threadIdx.x;
  const int wave = tid>>6, lane = tid&63;
  const int row16 = lane&15, quad = lane>>4;
  const int m_base = blockIdx.x*128 + wave*32;
  const int n_base = blockIdx.y*64;
  const bf16_t* Bw = Wt_all + (size_t)layer*NCOLS*Dd;

  floatx4 acc[2][4];
  #pragma unroll
  for (int mi=0;mi<2;mi++)
    #pragma unroll
    for (int ni=0;ni<4;ni++){ floatx4 z = {0.f,0.f,0.f,0.f}; acc[mi][ni] = z; }

  const bf16_t* a0p = A  + (size_t)(m_base + row16)*Dd + quad*8;
  const bf16_t* bp  = Bw + (size_t)(n_base + row16)*Dd + quad*8;
  #pragma unroll
  for (int ks=0; ks<8; ks++){
    bf16x8 a0 = *(const bf16x8*)(a0p + ks*32);
    bf16x8 a1 = *(const bf16x8*)(a0p + 16*Dd + ks*32);
    #pragma unroll
    for (int ni=0;ni<4;ni++){
      bf16x8 b = *(const bf16x8*)(bp + (size_t)ni*16*Dd + ks*32);
      acc[0][ni] = __builtin_amdgcn_mfma_f32_16x16x32_bf16(a0, b, acc[0][ni], 0,0,0);
      acc[1][ni] = __builtin_amdgcn_mfma_f32_16x16x32_bf16(a1, b, acc[1][ni], 0,0,0);
    }
  }

  const int by = blockIdx.y;
  const int bb = m_base >> 10;
  #pragma unroll
  for (int mi=0;mi<2;mi++)
    #pragma unroll
    for (int ni=0;ni<4;ni++){
      int col = n_base + ni*16 + row16;
      #pragma unroll
      for (int r=0;r<4;r++){
        int row = m_base + mi*16 + quad*4 + r;
        float v = acc[mi][ni][r];
        if (by < 4)       vproj_f[(size_t)row*256 + col]        = v;
        else if (by < 6)  hsrc_bf[(size_t)row*128 + (col-256)]  = (bf16_t)v;
        else if (by < 8)  hdst_f[(size_t)row*128 + (col-384)]   = v + t_hd[(size_t)(layer*Bb + bb)*HIDh + (col-384)];
        else              qw_bf[(size_t)row*1024 + (col-512)]   = (bf16_t)v;
      }
    }
}

// ---------------- fused upd(lu) + proj(lp=lu+1): 32 rows/block, 3-way col split ----------------
// grid (256, 3). Each y-block redundantly computes Phase U (reads node_in, stable),
// yb==0 writes node_out; each handles P col-chunks {yb*2, yb*2+1}.
__global__ __launch_bounds__(256) void gemm_updproj(
    const bf16_t* __restrict__ agg_bf, const bf16_t* __restrict__ Wto,
    const float* __restrict__ node_in, float* __restrict__ node_out,
    const bf16_t* __restrict__ Wt_all,
    float* __restrict__ vproj_f, bf16_t* __restrict__ hsrc_bf,
    float* __restrict__ hdst_f, bf16_t* __restrict__ qw_bf,
    const float* __restrict__ t_hd, int lu, int write_node){

  __shared__ __align__(16) bf16_t s_n[32*264];
  const int tid = threadIdx.x;
  const int wave = tid>>6, lane = tid&63;
  const int row16 = lane&15, quad = lane>>4;
  const int m0 = blockIdx.x*32;
  const int yb = blockIdx.y;
  const int lp = lu + 1;
  const int bb = m0 >> 10;

  // ---- Phase U (redundant per y-block; deterministic) ----
  {
    const bf16_t* Bw = Wto + (size_t)lu*Dd*Dd;
    floatx4 acc[2][4];
    #pragma unroll
    for (int mi=0;mi<2;mi++)
      #pragma unroll
      for (int ni=0;ni<4;ni++){ floatx4 z = {0.f,0.f,0.f,0.f}; acc[mi][ni] = z; }
    const bf16_t* a0p = agg_bf + (size_t)(m0 + row16)*Dd + quad*8;
    const bf16_t* bp  = Bw + (size_t)(wave*64 + row16)*Dd + quad*8;
    #pragma unroll
    for (int ks=0; ks<8; ks++){
      bf16x8 a0 = *(const bf16x8*)(a0p + ks*32);
      bf16x8 a1 = *(const bf16x8*)(a0p + 16*Dd + ks*32);
      #pragma unroll
      for (int ni=0;ni<4;ni++){
        bf16x8 b = *(const bf16x8*)(bp + (size_t)ni*16*Dd + ks*32);
        acc[0][ni] = __builtin_amdgcn_mfma_f32_16x16x32_bf16(a0, b, acc[0][ni], 0,0,0);
        acc[1][ni] = __builtin_amdgcn_mfma_f32_16x16x32_bf16(a1, b, acc[1][ni], 0,0,0);
      }
    }
    #pragma unroll
    for (int mi=0;mi<2;mi++)
      #pragma unroll
      for (int ni=0;ni<4;ni++){
        int col = wave*64 + ni*16 + row16;
        #pragma unroll
        for (int r=0;r<4;r++){
          int lr  = mi*16 + quad*4 + r;
          int row = m0 + lr;
          float v = acc[mi][ni][r] + node_in[(size_t)row*Dd + col];
          if (col < 64)       v = gelu_fast(v);
          else if (col < 128) v = tanh_fast(v);
          if (write_node && yb == 0) node_out[(size_t)row*Dd + col] = v;
          s_n[lr*264 + col] = (bf16_t)v;
        }
      }
  }
  __syncthreads();

  // ---- Phase P: 2 col-chunks for this y-block ----
  #pragma unroll 1
  for (int ci=0; ci<2; ci++){
    const int c = yb*2 + ci;
    const int colbase = c*256 + wave*64;
    floatx4 acc[2][4];
    #pragma unroll
    for (int mi=0;mi<2;mi++)
      #pragma unroll
      for (int ni=0;ni<4;ni++){ floatx4 z = {0.f,0.f,0.f,0.f}; acc[mi][ni] = z; }
    const bf16_t* bp = Wt_all + (size_t)lp*NCOLS*Dd + (size_t)(colbase + row16)*Dd + quad*8;
    #pragma unroll
    for (int ks=0; ks<8; ks++){
      bf16x8 a0 = *(const bf16x8*)&s_n[row16*264 + quad*8 + ks*32];
      bf16x8 a1 = *(const bf16x8*)&s_n[(16+row16)*264 + quad*8 + ks*32];
      #pragma unroll
      for (int ni=0;ni<4;ni++){
        bf16x8 b = *(const bf16x8*)(bp + (size_t)ni*16*Dd + ks*32);
        acc[0][ni] = __builtin_amdgcn_mfma_f32_16x16x32_bf16(a0, b, acc[0][ni], 0,0,0);
        acc[1][ni] = __builtin_amdgcn_mfma_f32_16x16x32_bf16(a1, b, acc[1][ni], 0,0,0);
      }
    }
    #pragma unroll
    for (int mi=0;mi<2;mi++)
      #pragma unroll
      for (int ni=0;ni<4;ni++){
        int col = colbase + ni*16 + row16;
        #pragma unroll
        for (int r=0;r<4;r++){
          int row = m0 + mi*16 + quad*4 + r;
          float v = acc[mi][ni][r];
          if (colbase < 256)      vproj_f[(size_t)row*256 + col]       = v;
          else if (colbase < 384) hsrc_bf[(size_t)row*128 + (col-256)] = (bf16_t)v;
          else if (colbase < 512) hdst_f[(size_t)row*128 + (col-384)]  = v + t_hd[(size_t)(lp*Bb + bb)*HIDh + (col-384)];
          else                    qw_bf[(size_t)row*1024 + (col-512)]  = (bf16_t)v;
        }
      }
  }
}

// ---------------- attn: block per node ----------------
__global__ __launch_bounds__(256) void attn_kernel(
    const float* __restrict__ x, const int* __restrict__ src,
    const float* __restrict__ vproj_f, const bf16_t* __restrict__ hsrc_bf,
    const float* __restrict__ hdst_f, const bf16_t* __restrict__ qw_bf,
    const bf16_t* __restrict__ WrbfT,
    const float* __restrict__ Wvg, const float* __restrict__ Woo,
    bf16_t* __restrict__ agg_bf, float* __restrict__ out, int layer){

  __shared__ __align__(16) char smem[11632];
  bf16_t* s_h     = (bf16_t*)(smem);
  float*  s_sh    = (float*)(smem + 8704);
  float*  s_cut   = (float*)(smem + 9984);
  int*    s_srcv  = (int*)  (smem + 10112);
  float*  s_logit = (float*)(smem + 10240);
  float*  s_poolsh= (float*)(smem + 11264);
  float*  s_red   = (float*)(smem + 11584);

  const int tid = threadIdx.x;
  const int bn  = blockIdx.x;
  const int b   = bn >> 10;
  const int wave = tid>>6, lane = tid&63;
  const int row16 = lane&15, quad = lane>>4;

  const float ax = x[(size_t)bn*3+0], ay = x[(size_t)bn*3+1], az = x[(size_t)bn*3+2];

  const int hr = tid>>4;
  const int hc = tid&15;
  const int sH0 = src[(size_t)bn*Kk + hr];
  const int sH1 = src[(size_t)bn*Kk + hr + 16];
  const int sE0 = src[(size_t)bn*Kk + row16];
  const int sE1 = src[(size_t)bn*Kk + row16 + 16];
  bf16x8 hsv0 = *(const bf16x8*)(hsrc_bf + ((size_t)b*Nn + sH0)*128 + hc*8);
  bf16x8 hsv1 = *(const bf16x8*)(hsrc_bf + ((size_t)b*Nn + sH1)*128 + hc*8);

  // rbf A-fragments via Gaussian recurrence
  bf16x8 a0f, a1f;
  {
    const float* xj0 = x + ((size_t)b*Nn + sE0)*3;
    const float* xj1 = x + ((size_t)b*Nn + sE1)*3;
    float d0x = ax - xj0[0], d0y = ay - xj0[1], d0z = az - xj0[2];
    float d1x = ax - xj1[0], d1y = ay - xj1[1], d1z = az - xj1[2];
    float rr0 = sqrtf(d0x*d0x + d0y*d0y + d0z*d0z);
    float rr1 = sqrtf(d1x*d1x + d1y*d1y + d1z*d1z);
    float xx0 = 10.0f*(1.0f - rr0*0.5f);
    float xx1 = 10.0f*(1.0f - rr1*0.5f);
    float cu0 = (xx0 > 0.0f) ? 1.4f*__expf(-__builtin_amdgcn_rcpf(xx0)) : 0.0f;
    float cu1 = (xx1 > 0.0f) ? 1.4f*__expf(-__builtin_amdgcn_rcpf(xx1)) : 0.0f;
    float sc0 = 4.798224586623f*cu0;
    float sc1 = 4.798224586623f*cu1;
    float rs0 = fminf(rr0*15.5f, 33.0f);
    float rs1 = fminf(rr1*15.5f, 33.0f);
    float cbase = (float)(quad*8);
    float dd0 = rs0 - cbase, dd1 = rs1 - cbase;
    float e0 = __expf(-dd0*dd0)*sc0;
    float e1 = __expf(-dd1*dd1)*sc1;
    float g0 = __expf(2.0f*dd0 - 1.0f);
    float g1 = __expf(2.0f*dd1 - 1.0f);
    a0f[0] = (bf16_t)e0; a1f[0] = (bf16_t)e1;
    #pragma unroll
    for (int j=1;j<8;j++){
      e0 *= g0; e1 *= g1;
      a0f[j] = (bf16_t)e0; a1f[j] = (bf16_t)e1;
      g0 *= 0.13533528323661270f; g1 *= 0.13533528323661270f;
    }
  }

  if (tid < 32){
    int k = tid;
    int j = src[(size_t)bn*Kk + k];
    s_srcv[k] = j;
    const float* xj = x + ((size_t)b*Nn + j)*3;
    float dx = ax - xj[0], dy = ay - xj[1], dz = az - xj[2];
    float rr = sqrtf(dx*dx + dy*dy + dz*dz);
    float xx = 10.0f*(1.0f - rr*0.5f);
    s_cut[k] = (xx > 0.0f) ? 1.4f*__expf(-__builtin_amdgcn_rcpf(xx)) : 0.0f;
  } else if (tid < 64){
    int k = tid - 32;
    int j = src[(size_t)bn*Kk + k];
    const float* xj = x + ((size_t)b*Nn + j)*3;
    float dx = ax - xj[0], dy = ay - xj[1], dz = az - xj[2];
    float rr = sqrtf(dx*dx + dy*dy + dz*dz);
    float inv = __builtin_amdgcn_rcpf(fmaxf(rr, 1e-9f));
    float ux = dx*inv, uy = dy*inv, uz = dz*inv;
    float* sh = s_sh + k*10;
    sh[0] = 1.0f;
    sh[1] = 1.7320508075688772f*ux;
    sh[2] = 1.7320508075688772f*uy;
    sh[3] = 1.7320508075688772f*uz;
    sh[4] = 3.872983346207417f*ux*uy;
    sh[5] = 3.872983346207417f*uy*uz;
    sh[6] = 1.118033988749895f*(3.0f*uz*uz - 1.0f);
    sh[7] = 3.872983346207417f*ux*uz;
    sh[8] = 1.9364916731037085f*(ux*ux - uy*uy);
  }

  floatx4 acc[2][2];
  {
    #pragma unroll
    for (int mi=0;mi<2;mi++)
      #pragma unroll
      for (int ni=0;ni<2;ni++){ floatx4 z = {0.f,0.f,0.f,0.f}; acc[mi][ni] = z; }
    const bf16_t* bp = WrbfT + ((size_t)layer*HIDh + wave*32 + row16)*NBnb + quad*8;
    bf16x8 b0 = *(const bf16x8*)(bp);
    bf16x8 b1 = *(const bf16x8*)(bp + 16*NBnb);
    acc[0][0] = __builtin_amdgcn_mfma_f32_16x16x32_bf16(a0f, b0, acc[0][0], 0,0,0);
    acc[0][1] = __builtin_amdgcn_mfma_f32_16x16x32_bf16(a0f, b1, acc[0][1], 0,0,0);
    acc[1][0] = __builtin_amdgcn_mfma_f32_16x16x32_bf16(a1f, b0, acc[1][0], 0,0,0);
    acc[1][1] = __builtin_amdgcn_mfma_f32_16x16x32_bf16(a1f, b1, acc[1][1], 0,0,0);
  }
  *(bf16x8*)(s_h + hr*136 + hc*8)      = hsv0;
  *(bf16x8*)(s_h + (hr+16)*136 + hc*8) = hsv1;
  __syncthreads();

  #pragma unroll
  for (int ni=0;ni<2;ni++){
    int c = wave*32 + ni*16 + row16;
    float hdv = hdst_f[(size_t)bn*128 + c];
    #pragma unroll
    for (int mi=0;mi<2;mi++){
      #pragma unroll
      for (int r=0;r<4;r++){
        int e = mi*16 + quad*4 + r;
        float hs = (float)s_h[e*136 + c];
        s_h[e*136 + c] = (bf16_t)gelu_fast(acc[mi][ni][r] + hdv + hs);
      }
    }
  }
  __syncthreads();

  if (wave < 2){
    floatx4 la = {0.f,0.f,0.f,0.f};
    const bf16_t* qp = qw_bf + (size_t)bn*1024 + row16*HIDh + quad*8;
    #pragma unroll
    for (int ks=0; ks<4; ks++){
      bf16x8 a = *(const bf16x8*)(s_h + (wave*16 + row16)*136 + ks*32 + quad*8);
      bf16x8 bq = *(const bf16x8*)(qp + ks*32);
      la = __builtin_amdgcn_mfma_f32_16x16x32_bf16(a, bq, la, 0,0,0);
    }
    if (row16 < Hh){
      #pragma unroll
      for (int r=0;r<4;r++)
        s_logit[(wave*16 + quad*4 + r)*8 + row16] = la[r]*0.17677669529663687f;
    }
  }
  __syncthreads();

  {
    const int l = tid & 63;
    const int k = l & 31;
    const int h = tid >> 5;
    float lv = s_logit[k*8 + h];
    float m = lv;
    #pragma unroll
    for (int off=16; off>=1; off>>=1) m = fmaxf(m, __shfl_xor(m, off));
    float w = s_cut[k]*__expf(lv - m);
    float ss = w;
    #pragma unroll
    for (int off=16; off>=1; off>>=1) ss += __shfl_xor(ss, off);
    float alpha = w*__builtin_amdgcn_rcpf(ss + 1e-9f);

    s_logit[k*8 + h] = alpha;   // same half-wave group re-reads below: in-order within wave

    const int sgi = (k < SHDs) ? k : 0;
    float a_m0 = 0.0f, a_m1 = 0.0f, a_sh = 0.0f;
    #pragma unroll
    for (int kk=0; kk<Kk; kk+=2){
      float av0 = s_logit[kk*8 + h];
      float av1 = s_logit[(kk+1)*8 + h];
      a_m0 += av0 * vproj_f[((size_t)b*Nn + s_srcv[kk])*256 + tid];
      a_m1 += av1 * vproj_f[((size_t)b*Nn + s_srcv[kk+1])*256 + tid];
      a_sh += av0 * s_sh[kk*10 + sgi] + av1 * s_sh[(kk+1)*10 + sgi];
    }
    float a_main = a_m0 + a_m1;
    if (k < SHDs) s_poolsh[h*10 + k] = a_sh;

    const float* wvsh = Wvg + (size_t)layer*265*Dd + 256*Dd;
    #pragma unroll
    for (int sg=0; sg<SHDs; sg++) a_main += s_poolsh[h*10 + sg]*wvsh[sg*Dd + tid];

    if (layer < 3){
      agg_bf[(size_t)bn*Dd + tid] = (bf16_t)a_main;
    } else {
      float p0 = a_main*Woo[tid*3+0];
      float p1 = a_main*Woo[tid*3+1];
      float p2 = a_main*Woo[tid*3+2];
      #pragma unroll
      for (int off=32; off>=1; off>>=1){
        p0 += __shfl_xor(p0, off);
        p1 += __shfl_xor(p1, off);
        p2 += __shfl_xor(p2, off);
      }
      if (lane == 0){ s_red[wave*3+0]=p0; s_red[wave*3+1]=p1; s_red[wave*3+2]=p2; }
      __syncthreads();
      if (tid < 3)
        out[(size_t)bn*3 + tid] = s_red[0*3+tid]+s_red[1*3+tid]+s_red[2*3+tid]+s_red[3*3+tid];
    }
  }
}

extern "C" void kernel_launch(void* const* d_in, const int* in_sizes, int n_in,
                              void* d_out, int out_size, void* d_ws, size_t ws_size,
                              hipStream_t stream){
  const float* x   = (const float*)d_in[0];
  const float* y   = (const float*)d_in[1];
  const float* t   = (const float*)d_in[2];
  const float* We  = (const float*)d_in[3];
  const float* Wk1 = (const float*)d_in[4];
  const float* bk1 = (const float*)d_in[5];
  const float* Wk2 = (const float*)d_in[6];
  const float* Wq  = (const float*)d_in[7];
  const float* Wv  = (const float*)d_in[8];
  const float* Wo  = (const float*)d_in[9];
  const float* Woo = (const float*)d_in[10];
  float* out = (float*)d_out;

  char* ws = (char*)d_ws;
  size_t off = 0;
  auto take = [&](size_t bytes)->char*{ char* p = ws + off; off = (off + bytes + 255) & ~(size_t)255; return p; };

  int*    src      = (int*)   take((size_t)Bb*Nn*Kk*4);
  float*  nodeA    = (float*) take((size_t)Bb*Nn*Dd*4);
  float*  nodeB    = (float*) take((size_t)Bb*Nn*Dd*4);
  bf16_t* node_bf  = (bf16_t*)take((size_t)Bb*Nn*Dd*2);
  bf16_t* agg_bf   = (bf16_t*)take((size_t)Bb*Nn*Dd*2);
  float*  vproj_f  = (float*) take((size_t)Bb*Nn*256*4);
  bf16_t* hsrc_bf  = (bf16_t*)take((size_t)Bb*Nn*128*2);
  float*  hdst_f   = (float*) take((size_t)Bb*Nn*128*4);
  bf16_t* qw_bf    = (bf16_t*)take(((size_t)Bb*Nn*1024 + 2048)*2);  // +pad for B-frag overread
  bf16_t* Wt       = (bf16_t*)take((size_t)4*NCOLS*Dd*2);
  bf16_t* Wto      = (bf16_t*)take((size_t)3*Dd*Dd*2);
  bf16_t* WrbfT    = (bf16_t*)take((size_t)4*HIDh*NBnb*2);
  float*  t_hd     = (float*) take((size_t)4*Bb*HIDh*4);

  setup_kernel<<<dim3(11088), 256, 0, stream>>>(x, y, t, We, Wk1, bk1, Wk2, Wq, Wv, Wo,
                                                Wt, Wto, WrbfT, t_hd, src, nodeA, node_bf);

  gemm_proj<<<dim3(64,24), 256, 0, stream>>>(node_bf, Wt, vproj_f, hsrc_bf, hdst_f, qw_bf, t_hd, 0);
  attn_kernel<<<dim3(Bb*Nn), 256, 0, stream>>>(x, src, vproj_f, hsrc_bf, hdst_f, qw_bf,
                                               WrbfT, Wv, Woo, agg_bf, out, 0);
  // double-buffered node: lu=0 reads A writes B; lu=1 reads B writes A; lu=2 reads A (no write)
  const float* nin[3]  = {nodeA, nodeB, nodeA};
  float*       nout[3] = {nodeB, nodeA, nodeB};
  for (int l=1; l<4; l++){
    gemm_updproj<<<dim3(Bb*Nn/32, 3), 256, 0, stream>>>(agg_bf, Wto, nin[l-1], nout[l-1], Wt,
                                                        vproj_f, hsrc_bf, hdst_f, qw_bf, t_hd, l-1,
                                                        (l < 3) ? 1 : 0);
    attn_kernel<<<dim3(Bb*Nn), 256, 0, stream>>>(x, src, vproj_f, hsrc_bf, hdst_f, qw_bf,
                                                 WrbfT, Wv, Woo, agg_bf, out, l);
  }
}